// Round 3
// baseline (1253.101 us; speedup 1.0000x reference)
//
#include <hip/hip_runtime.h>

#define N_NODES 50000
#define N_EDGES 800000
#define D_MODEL 256
#define H_HEADS 8
#define C_CH 32
#define DE_DIM 64
#define NEG_SLOPE 0.2f
#define LN_EPS 1e-5f
#define TILES (N_EDGES / 64)   // 12500 exact

typedef float  f32x4  __attribute__((ext_vector_type(4)));
typedef short  bf16x8 __attribute__((ext_vector_type(8)));

static __device__ __forceinline__ unsigned short f2bf(float f) {
    unsigned int u = __float_as_uint(f);
    u += 0x7fffu + ((u >> 16) & 1u);   // RNE
    return (unsigned short)(u >> 16);
}
static __device__ __forceinline__ float bf2f(unsigned short s) {
    return __uint_as_float(((unsigned int)s) << 16);
}
static __device__ __forceinline__ bf16x8 load_cvt8(const float* __restrict__ p) {
    float4 a = *(const float4*)p;
    float4 b = *(const float4*)(p + 4);
    bf16x8 r;
    r[0] = (short)f2bf(a.x); r[1] = (short)f2bf(a.y);
    r[2] = (short)f2bf(a.z); r[3] = (short)f2bf(a.w);
    r[4] = (short)f2bf(b.x); r[5] = (short)f2bf(b.y);
    r[6] = (short)f2bf(b.z); r[7] = (short)f2bf(b.w);
    return r;
}

// ---------- Kernel 0: fp32 -> bf16 bulk convert ----------
__global__ __launch_bounds__(256) void cvt_bf16_kernel(const float* __restrict__ in,
                                                       unsigned short* __restrict__ out,
                                                       int n8) {
    int g = blockIdx.x * 256 + threadIdx.x;
    if (g < n8) {
        bf16x8 v = load_cvt8(in + (size_t)g * 8);
        *(bf16x8*)(out + (size_t)g * 8) = v;
    }
}

// ---------- Kernel 1: node GEMMs (xl, xr, res) via bf16 MFMA ----------
__global__ __launch_bounds__(256) void node_gemm(const unsigned short* __restrict__ xbf,
                                                 const unsigned short* __restrict__ Wbf, // [3][256*256]
                                                 const float* __restrict__ bl,
                                                 const float* __restrict__ br,
                                                 unsigned short* __restrict__ xl,
                                                 unsigned short* __restrict__ xr,
                                                 float* __restrict__ res) {
    int tid = threadIdx.x;
    int lane = tid & 63, wv = tid >> 6;
    int quad = lane >> 4, l15 = lane & 15;
    int rowTile = blockIdx.x * 64;
    int which = blockIdx.y;
    const unsigned short* W = Wbf + (size_t)which * 65536;
    int colBase = wv * 64;

    f32x4 acc[4][4];
#pragma unroll
    for (int r = 0; r < 4; r++)
#pragma unroll
        for (int c = 0; c < 4; c++) acc[r][c] = (f32x4){0.f, 0.f, 0.f, 0.f};

#pragma unroll 1
    for (int k8 = 0; k8 < 8; ++k8) {
        int kb = k8 * 32 + quad * 8;
        bf16x8 af[4], bfr[4];
#pragma unroll
        for (int r = 0; r < 4; r++) {
            int row = rowTile + r * 16 + l15;
            if (row > N_NODES - 1) row = N_NODES - 1;
            af[r] = *(const bf16x8*)(xbf + (size_t)row * D_MODEL + kb);
        }
#pragma unroll
        for (int c = 0; c < 4; c++) {
            int col = colBase + c * 16 + l15;
            bfr[c] = *(const bf16x8*)(W + (size_t)col * D_MODEL + kb);
        }
#pragma unroll
        for (int r = 0; r < 4; r++)
#pragma unroll
            for (int c = 0; c < 4; c++)
                acc[r][c] = __builtin_amdgcn_mfma_f32_16x16x32_bf16(af[r], bfr[c], acc[r][c], 0, 0, 0);
    }

    float bv[4];
#pragma unroll
    for (int c = 0; c < 4; c++) {
        int col = colBase + c * 16 + l15;
        bv[c] = (which == 0) ? bl[col] : (which == 1 ? br[col] : 0.f);
    }
#pragma unroll
    for (int r = 0; r < 4; r++) {
#pragma unroll
        for (int g = 0; g < 4; g++) {
            int row = rowTile + r * 16 + quad * 4 + g;
            if (row < N_NODES) {
#pragma unroll
                for (int c = 0; c < 4; c++) {
                    int col = colBase + c * 16 + l15;
                    float v = acc[r][c][g] + bv[c];
                    size_t idx = (size_t)row * D_MODEL + col;
                    if (which == 0)      xl[idx] = f2bf(v);
                    else if (which == 1) xr[idx] = f2bf(v);
                    else                 res[idx] = v;
                }
            }
        }
    }
}

// ---------- Kernel 2: fused edge GEMM + GATv2 attention logits ----------
// Round-0 structure (edge-order iteration, lane owns channel-column, 4 edges)
// minus the dead weight:
//  * edge_attr A-fragments loaded straight from global (the old aS LDS
//    round-trip wrote and re-read the SAME lane/index). Edge-order keeps
//    this read dense: each wave covers 16 full rows (4 KB) in 2 loads.
//  * zero per-tile barriers (weS/attS read-only after the initial sync).
//  * __launch_bounds__(256,4) caps VGPR at 128 so cross-tile pipelining
//    cannot eat residency: 33 KB LDS + <=128 VGPR -> 4 blocks/CU.
__global__ __launch_bounds__(256, 4) void edge_logits(const float* __restrict__ edge_attr,
                                                      const float* __restrict__ We,   // [256][64]
                                                      const float* __restrict__ att,  // [256] flat
                                                      const int* __restrict__ srcIdx,
                                                      const int* __restrict__ dstIdx,
                                                      const int* __restrict__ posOf,
                                                      const unsigned short* __restrict__ xl,
                                                      const unsigned short* __restrict__ xr,
                                                      float* __restrict__ alphaP) {
    __shared__ short weS[2048 * 8];      // fragment-linear, 32 KB
    __shared__ float attS[256];

    int tid = threadIdx.x;
    int lane = tid & 63, wv = tid >> 6;
    int quad = lane >> 4, l15 = lane & 15;

    for (int g = tid; g < 2048; g += 256) {
        int c = g >> 7, kq = (g >> 6) & 1, ln = g & 63;
        int o = c * 16 + (ln & 15);
        int k = kq * 32 + (ln >> 4) * 8;
        bf16x8 v = load_cvt8(We + o * DE_DIM + k);
        *(bf16x8*)&weS[g * 8] = v;
    }
    if (tid < 256) attS[tid] = att[tid];
    __syncthreads();

    for (int tile = blockIdx.x; tile < TILES; tile += gridDim.x) {
        int e0 = tile * 64 + wv * 16;

        // A-fragment: lane holds edge row e0+l15, k-chunk quad*8 (dense 4 KB/wave)
        int eA = e0 + l15;
        bf16x8 a0 = load_cvt8(edge_attr + (size_t)eA * DE_DIM + quad * 8);
        bf16x8 a1 = load_cvt8(edge_attr + (size_t)eA * DE_DIM + 32 + quad * 8);

        int srcv[4], dstv[4], posv[4];
#pragma unroll
        for (int r = 0; r < 4; r++) {
            int e = e0 + quad * 4 + r;
            srcv[r] = srcIdx[e];
            dstv[r] = dstIdx[e];
            posv[r] = posOf[e];
        }

        float pa[4][8];
#pragma unroll
        for (int r = 0; r < 4; r++)
#pragma unroll
            for (int h = 0; h < 8; h++) pa[r][h] = 0.f;

#pragma unroll
        for (int c = 0; c < 16; c++) {
            bf16x8 b0 = *(bf16x8*)&weS[((c * 2 + 0) * 64 + lane) * 8];
            bf16x8 b1 = *(bf16x8*)&weS[((c * 2 + 1) * 64 + lane) * 8];
            f32x4 ee = (f32x4){0.f, 0.f, 0.f, 0.f};
            ee = __builtin_amdgcn_mfma_f32_16x16x32_bf16(a0, b0, ee, 0, 0, 0);
            ee = __builtin_amdgcn_mfma_f32_16x16x32_bf16(a1, b1, ee, 0, 0, 0);
            int col = c * 16 + l15;
            float attvc = attS[col];
#pragma unroll
            for (int r = 0; r < 4; r++) {
                float xlv = bf2f(xl[(size_t)srcv[r] * D_MODEL + col]);
                float xrv = bf2f(xr[(size_t)dstv[r] * D_MODEL + col]);
                float t = ee[r] + xlv + xrv;
                t = (t > 0.f) ? t : NEG_SLOPE * t;
                pa[r][c >> 1] += t * attvc;
            }
        }
#pragma unroll
        for (int r = 0; r < 4; r++)
#pragma unroll
            for (int h = 0; h < 8; h++) {
                float v = pa[r][h];
                v += __shfl_xor(v, 1);
                v += __shfl_xor(v, 2);
                v += __shfl_xor(v, 4);
                v += __shfl_xor(v, 8);
                pa[r][h] = v;
            }
        if (l15 == 0) {
#pragma unroll
            for (int r = 0; r < 4; r++) {
                size_t pos = (size_t)posv[r];
                *(float4*)(alphaP + pos * 8)     = make_float4(pa[r][0], pa[r][1], pa[r][2], pa[r][3]);
                *(float4*)(alphaP + pos * 8 + 4) = make_float4(pa[r][4], pa[r][5], pa[r][6], pa[r][7]);
            }
        }
    }
}

// ---------- CSR build ----------
__global__ __launch_bounds__(256) void hist_kernel(const int* __restrict__ dstIdx,
                                                   int* __restrict__ cnt) {
    int e = blockIdx.x * 256 + threadIdx.x;
    if (e < N_EDGES) atomicAdd(&cnt[dstIdx[e]], 1);
}

// single-block scan, thread-serial chunks (49 elems/thread) + shfl block scan
__global__ __launch_bounds__(1024) void scan_kernel(const int* __restrict__ cnt,
                                                    int* __restrict__ off,
                                                    int* __restrict__ woff) {
    const int CHUNK = 49;   // 49*1024 = 50176 >= 50000
    int tid = threadIdx.x;
    int base = tid * CHUNK;
    int local[CHUNK];
    int sum = 0;
#pragma unroll
    for (int j = 0; j < CHUNK; ++j) {
        int idx = base + j;
        int v = (idx < N_NODES) ? cnt[idx] : 0;
        local[j] = sum;
        sum += v;
    }
    int lane = tid & 63, wv = tid >> 6;
    int s = sum;
#pragma unroll
    for (int ofs = 1; ofs < 64; ofs <<= 1) {
        int t2 = __shfl_up(s, ofs);
        if (lane >= ofs) s += t2;
    }
    __shared__ int wsum[16];
    __shared__ int woffS[16];
    if (lane == 63) wsum[wv] = s;
    __syncthreads();
    if (tid == 0) {
        int a = 0;
#pragma unroll
        for (int i = 0; i < 16; ++i) { woffS[i] = a; a += wsum[i]; }
    }
    __syncthreads();
    int excl = woffS[wv] + (s - sum);   // exclusive prefix of this thread's chunk
#pragma unroll
    for (int j = 0; j < CHUNK; ++j) {
        int idx = base + j;
        if (idx < N_NODES) {
            int v = excl + local[j];
            off[idx] = v;
            woff[idx] = v;
        }
    }
    if (tid == 0) off[N_NODES] = N_EDGES;
}

__global__ __launch_bounds__(256) void scatter_kernel(const int* __restrict__ srcIdx,
                                                      const int* __restrict__ dstIdx,
                                                      int* __restrict__ woff,
                                                      int* __restrict__ posOf,
                                                      int* __restrict__ srcP) {
    int e = blockIdx.x * 256 + threadIdx.x;
    if (e < N_EDGES) {
        int pos = atomicAdd(&woff[dstIdx[e]], 1);
        posOf[e] = pos;
        srcP[pos] = srcIdx[e];
    }
}

// ---------- Kernel 4: node-centric softmax + aggregation + residual + LayerNorm ----------
// One WAVE per node, 4 channels per lane. Zero LDS, zero barriers; xl gather
// is one 8B vector load per lane (512B coalesced per wave per edge).
// srcP/alphaP indirection software-pipelined depth 2.
__global__ __launch_bounds__(256) void aggregate_ln(const int* __restrict__ off,
                                                    const int* __restrict__ srcP,
                                                    const float* __restrict__ alphaP,
                                                    const unsigned short* __restrict__ xl,
                                                    const float* __restrict__ res,
                                                    const float* __restrict__ biasc,
                                                    const float* __restrict__ gamma,
                                                    const float* __restrict__ beta,
                                                    float* __restrict__ out) {
    int wv = threadIdx.x >> 6, lane = threadIdx.x & 63;
    int i = blockIdx.x * 4 + wv;            // 12500 blocks * 4 waves = 50000 exact
    int beg = off[i], end = off[i + 1];
    int h = lane >> 3;                      // head of channels lane*4..lane*4+3

    float acc0 = 0.f, acc1 = 0.f, acc2 = 0.f, acc3 = 0.f, s = 0.f;

    int p = beg;
    int src_n = 0; float a_n = 0.f;
    if (p < end) {
        src_n = srcP[p];
        a_n   = alphaP[(size_t)p * 8 + h];
    }
    while (p < end) {
        int src = src_n; float a = a_n;
        int pn = p + 1;
        if (pn < end) {                     // prefetch next indirection
            src_n = srcP[pn];
            a_n   = alphaP[(size_t)pn * 8 + h];
        }
        ushort4 v = *(const ushort4*)(xl + (size_t)src * D_MODEL + lane * 4);
        float w = __expf(a);
        s += w;
        acc0 = fmaf(w, bf2f(v.x), acc0);
        acc1 = fmaf(w, bf2f(v.y), acc1);
        acc2 = fmaf(w, bf2f(v.z), acc2);
        acc3 = fmaf(w, bf2f(v.w), acc3);
        p = pn;
    }

    float rs = (end > beg) ? (1.f / s) : 0.f;
    float4 r4 = *(const float4*)(res + (size_t)i * D_MODEL + lane * 4);
    float4 b4 = *(const float4*)(biasc + lane * 4);
    float v0 = acc0 * rs + r4.x + b4.x;
    float v1 = acc1 * rs + r4.y + b4.y;
    float v2 = acc2 * rs + r4.z + b4.z;
    float v3 = acc3 * rs + r4.w + b4.w;

    // LayerNorm over 256 channels = full-wave reduce of per-lane 4-sums
    float sum = v0 + v1 + v2 + v3;
    float sq  = v0 * v0 + v1 * v1 + v2 * v2 + v3 * v3;
#pragma unroll
    for (int msk = 32; msk >= 1; msk >>= 1) {
        sum += __shfl_xor(sum, msk);
        sq  += __shfl_xor(sq, msk);
    }
    float mu  = sum * (1.f / 256.f);
    float var = sq * (1.f / 256.f) - mu * mu;
    var = fmaxf(var, 0.f);
    float inv = rsqrtf(var + LN_EPS);

    float4 g4 = *(const float4*)(gamma + lane * 4);
    float4 be4 = *(const float4*)(beta + lane * 4);
    float4 o4;
    o4.x = (v0 - mu) * inv * g4.x + be4.x;
    o4.y = (v1 - mu) * inv * g4.y + be4.y;
    o4.z = (v2 - mu) * inv * g4.z + be4.z;
    o4.w = (v3 - mu) * inv * g4.w + be4.w;
    *(float4*)(out + (size_t)i * D_MODEL + lane * 4) = o4;
}

extern "C" void kernel_launch(void* const* d_in, const int* in_sizes, int n_in,
                              void* d_out, int out_size, void* d_ws, size_t ws_size,
                              hipStream_t stream) {
    const float* x         = (const float*)d_in[0];
    const float* edge_attr = (const float*)d_in[1];
    const int*   edge_index= (const int*)d_in[2];
    const float* Wl        = (const float*)d_in[3];
    const float* bl        = (const float*)d_in[4];
    const float* Wr        = (const float*)d_in[5];
    const float* br        = (const float*)d_in[6];
    const float* We        = (const float*)d_in[7];
    const float* att       = (const float*)d_in[8];
    const float* Wres      = (const float*)d_in[9];
    const float* biasc     = (const float*)d_in[10];
    const float* gamma     = (const float*)d_in[11];
    const float* beta      = (const float*)d_in[12];
    const int* srcIdx = edge_index;
    const int* dstIdx = edge_index + N_EDGES;
    float* out = (float*)d_out;

    // workspace layout
    char* ws = (char*)d_ws;
    unsigned short* xl  = (unsigned short*)ws;                       // N*256 bf16
    unsigned short* xr  = xl + (size_t)N_NODES * D_MODEL;            // N*256 bf16
    unsigned short* xbf = xr + (size_t)N_NODES * D_MODEL;            // N*256 bf16
    unsigned short* Wbf = xbf + (size_t)N_NODES * D_MODEL;           // 3*256*256 bf16
    float* res    = (float*)(Wbf + 3 * 65536);                       // N*256 f32
    float* alphaP = res + (size_t)N_NODES * D_MODEL;                 // E*8 f32 (CSR order)
    int* cnt   = (int*)(alphaP + (size_t)N_EDGES * 8);               // N
    int* off   = cnt + N_NODES;                                      // N+1
    int* woff  = off + (N_NODES + 1);                                // N
    int* posOf = woff + N_NODES;                                     // E
    int* srcP  = posOf + N_EDGES;                                    // E
    (void)ws_size; (void)n_in; (void)in_sizes; (void)out_size;

    hipMemsetAsync(cnt, 0, N_NODES * sizeof(int), stream);

    cvt_bf16_kernel<<<(N_NODES * D_MODEL / 8 + 255) / 256, 256, 0, stream>>>(x, xbf, N_NODES * D_MODEL / 8);
    cvt_bf16_kernel<<<32, 256, 0, stream>>>(Wl,   Wbf,             65536 / 8);
    cvt_bf16_kernel<<<32, 256, 0, stream>>>(Wr,   Wbf + 65536,     65536 / 8);
    cvt_bf16_kernel<<<32, 256, 0, stream>>>(Wres, Wbf + 2 * 65536, 65536 / 8);

    dim3 g1((N_NODES + 63) / 64, 3);
    node_gemm<<<g1, 256, 0, stream>>>(xbf, Wbf, bl, br, xl, xr, res);

    hist_kernel<<<(N_EDGES + 255) / 256, 256, 0, stream>>>(dstIdx, cnt);
    scan_kernel<<<1, 1024, 0, stream>>>(cnt, off, woff);
    scatter_kernel<<<(N_EDGES + 255) / 256, 256, 0, stream>>>(srcIdx, dstIdx, woff, posOf, srcP);

    edge_logits<<<2500, 256, 0, stream>>>(edge_attr, We, att, srcIdx, dstIdx, posOf, xl, xr, alphaP);

    aggregate_ln<<<N_NODES / 4, 256, 0, stream>>>(off, srcP, alphaP, xl, res,
                                                  biasc, gamma, beta, out);
}

// Round 4
// 859.551 us; speedup vs baseline: 1.4579x; 1.4579x over previous
//
#include <hip/hip_runtime.h>

#define N_NODES 50000
#define N_EDGES 800000
#define D_MODEL 256
#define H_HEADS 8
#define C_CH 32
#define DE_DIM 64
#define NEG_SLOPE 0.2f
#define LN_EPS 1e-5f
#define TILES (N_EDGES / 64)   // 12500 exact

typedef float  f32x4  __attribute__((ext_vector_type(4)));
typedef short  bf16x8 __attribute__((ext_vector_type(8)));

static __device__ __forceinline__ unsigned short f2bf(float f) {
    unsigned int u = __float_as_uint(f);
    u += 0x7fffu + ((u >> 16) & 1u);   // RNE
    return (unsigned short)(u >> 16);
}
static __device__ __forceinline__ float bf2f(unsigned short s) {
    return __uint_as_float(((unsigned int)s) << 16);
}
static __device__ __forceinline__ bf16x8 load_cvt8(const float* __restrict__ p) {
    float4 a = *(const float4*)p;
    float4 b = *(const float4*)(p + 4);
    bf16x8 r;
    r[0] = (short)f2bf(a.x); r[1] = (short)f2bf(a.y);
    r[2] = (short)f2bf(a.z); r[3] = (short)f2bf(a.w);
    r[4] = (short)f2bf(b.x); r[5] = (short)f2bf(b.y);
    r[6] = (short)f2bf(b.z); r[7] = (short)f2bf(b.w);
    return r;
}

// ---------- Kernel 0: fp32 -> bf16 bulk convert ----------
__global__ __launch_bounds__(256) void cvt_bf16_kernel(const float* __restrict__ in,
                                                       unsigned short* __restrict__ out,
                                                       int n8) {
    int g = blockIdx.x * 256 + threadIdx.x;
    if (g < n8) {
        bf16x8 v = load_cvt8(in + (size_t)g * 8);
        *(bf16x8*)(out + (size_t)g * 8) = v;
    }
}

// ---------- Kernel 1: node GEMMs (xl, xr, res) via bf16 MFMA ----------
__global__ __launch_bounds__(256) void node_gemm(const unsigned short* __restrict__ xbf,
                                                 const unsigned short* __restrict__ Wbf, // [3][256*256]
                                                 const float* __restrict__ bl,
                                                 const float* __restrict__ br,
                                                 unsigned short* __restrict__ xl,
                                                 unsigned short* __restrict__ xr,
                                                 float* __restrict__ res) {
    int tid = threadIdx.x;
    int lane = tid & 63, wv = tid >> 6;
    int quad = lane >> 4, l15 = lane & 15;
    int rowTile = blockIdx.x * 64;
    int which = blockIdx.y;
    const unsigned short* W = Wbf + (size_t)which * 65536;
    int colBase = wv * 64;

    f32x4 acc[4][4];
#pragma unroll
    for (int r = 0; r < 4; r++)
#pragma unroll
        for (int c = 0; c < 4; c++) acc[r][c] = (f32x4){0.f, 0.f, 0.f, 0.f};

#pragma unroll 1
    for (int k8 = 0; k8 < 8; ++k8) {
        int kb = k8 * 32 + quad * 8;
        bf16x8 af[4], bfr[4];
#pragma unroll
        for (int r = 0; r < 4; r++) {
            int row = rowTile + r * 16 + l15;
            if (row > N_NODES - 1) row = N_NODES - 1;
            af[r] = *(const bf16x8*)(xbf + (size_t)row * D_MODEL + kb);
        }
#pragma unroll
        for (int c = 0; c < 4; c++) {
            int col = colBase + c * 16 + l15;
            bfr[c] = *(const bf16x8*)(W + (size_t)col * D_MODEL + kb);
        }
#pragma unroll
        for (int r = 0; r < 4; r++)
#pragma unroll
            for (int c = 0; c < 4; c++)
                acc[r][c] = __builtin_amdgcn_mfma_f32_16x16x32_bf16(af[r], bfr[c], acc[r][c], 0, 0, 0);
    }

    float bv[4];
#pragma unroll
    for (int c = 0; c < 4; c++) {
        int col = colBase + c * 16 + l15;
        bv[c] = (which == 0) ? bl[col] : (which == 1 ? br[col] : 0.f);
    }
#pragma unroll
    for (int r = 0; r < 4; r++) {
#pragma unroll
        for (int g = 0; g < 4; g++) {
            int row = rowTile + r * 16 + quad * 4 + g;
            if (row < N_NODES) {
#pragma unroll
                for (int c = 0; c < 4; c++) {
                    int col = colBase + c * 16 + l15;
                    float v = acc[r][c][g] + bv[c];
                    size_t idx = (size_t)row * D_MODEL + col;
                    if (which == 0)      xl[idx] = f2bf(v);
                    else if (which == 1) xr[idx] = f2bf(v);
                    else                 res[idx] = v;
                }
            }
        }
    }
}

// ---------- Kernel 2: fused edge GEMM + GATv2 attention logits ----------
// Round-0 structure (edge-order, lane owns channel-column, 4 edges/lane-group,
// attS in LDS, per-tile __syncthreads kept as a REGISTER-PRESSURE FENCE:
// every barrier-free variant inflated VGPR 116->160+ and halved occupancy).
// Single change vs round-0: the aS edge_attr LDS staging is deleted (each
// lane re-read exactly the element it wrote) -> A-fragments direct from
// global (dense 4 KB/wave). LDS 41984->33792 B => 4 blocks/CU instead of 3.
__global__ __launch_bounds__(256) void edge_logits(const float* __restrict__ edge_attr,
                                                   const float* __restrict__ We,   // [256][64]
                                                   const float* __restrict__ att,  // [256] flat
                                                   const int* __restrict__ srcIdx,
                                                   const int* __restrict__ dstIdx,
                                                   const int* __restrict__ posOf,
                                                   const unsigned short* __restrict__ xl,
                                                   const unsigned short* __restrict__ xr,
                                                   float* __restrict__ alphaP) {
    __shared__ short weS[2048 * 8];      // fragment-linear, 32 KB
    __shared__ float attS[256];

    int tid = threadIdx.x;
    int lane = tid & 63, wv = tid >> 6;
    int quad = lane >> 4, l15 = lane & 15;

    for (int g = tid; g < 2048; g += 256) {
        int c = g >> 7, kq = (g >> 6) & 1, ln = g & 63;
        int o = c * 16 + (ln & 15);
        int k = kq * 32 + (ln >> 4) * 8;
        bf16x8 v = load_cvt8(We + o * DE_DIM + k);
        *(bf16x8*)&weS[g * 8] = v;
    }
    if (tid < 256) attS[tid] = att[tid];
    __syncthreads();

    for (int tile = blockIdx.x; tile < TILES; tile += gridDim.x) {
        int e0 = tile * 64 + wv * 16;

        // A-fragment: lane holds edge row e0+l15, k-chunk quad*8 (dense 4 KB/wave)
        int eA = e0 + l15;
        bf16x8 a0 = load_cvt8(edge_attr + (size_t)eA * DE_DIM + quad * 8);
        bf16x8 a1 = load_cvt8(edge_attr + (size_t)eA * DE_DIM + 32 + quad * 8);

        int srcv[4], dstv[4], posv[4];
#pragma unroll
        for (int r = 0; r < 4; r++) {
            int e = e0 + quad * 4 + r;
            srcv[r] = srcIdx[e];
            dstv[r] = dstIdx[e];
            posv[r] = posOf[e];
        }

        float pa[4][8];
#pragma unroll
        for (int r = 0; r < 4; r++)
#pragma unroll
            for (int h = 0; h < 8; h++) pa[r][h] = 0.f;

#pragma unroll
        for (int c = 0; c < 16; c++) {
            bf16x8 b0 = *(bf16x8*)&weS[((c * 2 + 0) * 64 + lane) * 8];
            bf16x8 b1 = *(bf16x8*)&weS[((c * 2 + 1) * 64 + lane) * 8];
            f32x4 ee = (f32x4){0.f, 0.f, 0.f, 0.f};
            ee = __builtin_amdgcn_mfma_f32_16x16x32_bf16(a0, b0, ee, 0, 0, 0);
            ee = __builtin_amdgcn_mfma_f32_16x16x32_bf16(a1, b1, ee, 0, 0, 0);
            int col = c * 16 + l15;
            float attvc = attS[col];
#pragma unroll
            for (int r = 0; r < 4; r++) {
                float xlv = bf2f(xl[(size_t)srcv[r] * D_MODEL + col]);
                float xrv = bf2f(xr[(size_t)dstv[r] * D_MODEL + col]);
                float t = ee[r] + xlv + xrv;
                t = (t > 0.f) ? t : NEG_SLOPE * t;
                pa[r][c >> 1] += t * attvc;
            }
        }
#pragma unroll
        for (int r = 0; r < 4; r++)
#pragma unroll
            for (int h = 0; h < 8; h++) {
                float v = pa[r][h];
                v += __shfl_xor(v, 1);
                v += __shfl_xor(v, 2);
                v += __shfl_xor(v, 4);
                v += __shfl_xor(v, 8);
                pa[r][h] = v;
            }
        if (l15 == 0) {
#pragma unroll
            for (int r = 0; r < 4; r++) {
                size_t pos = (size_t)posv[r];
                *(float4*)(alphaP + pos * 8)     = make_float4(pa[r][0], pa[r][1], pa[r][2], pa[r][3]);
                *(float4*)(alphaP + pos * 8 + 4) = make_float4(pa[r][4], pa[r][5], pa[r][6], pa[r][7]);
            }
        }
        __syncthreads();   // register-pressure fence (see header comment)
    }
}

// ---------- CSR build ----------
__global__ __launch_bounds__(256) void hist_kernel(const int* __restrict__ dstIdx,
                                                   int* __restrict__ cnt) {
    int e = blockIdx.x * 256 + threadIdx.x;
    if (e < N_EDGES) atomicAdd(&cnt[dstIdx[e]], 1);
}

// single-block scan, thread-serial chunks (49 elems/thread) + shfl block scan
__global__ __launch_bounds__(1024) void scan_kernel(const int* __restrict__ cnt,
                                                    int* __restrict__ off,
                                                    int* __restrict__ woff) {
    const int CHUNK = 49;   // 49*1024 = 50176 >= 50000
    int tid = threadIdx.x;
    int base = tid * CHUNK;
    int local[CHUNK];
    int sum = 0;
#pragma unroll
    for (int j = 0; j < CHUNK; ++j) {
        int idx = base + j;
        int v = (idx < N_NODES) ? cnt[idx] : 0;
        local[j] = sum;
        sum += v;
    }
    int lane = tid & 63, wv = tid >> 6;
    int s = sum;
#pragma unroll
    for (int ofs = 1; ofs < 64; ofs <<= 1) {
        int t2 = __shfl_up(s, ofs);
        if (lane >= ofs) s += t2;
    }
    __shared__ int wsum[16];
    __shared__ int woffS[16];
    if (lane == 63) wsum[wv] = s;
    __syncthreads();
    if (tid == 0) {
        int a = 0;
#pragma unroll
        for (int i = 0; i < 16; ++i) { woffS[i] = a; a += wsum[i]; }
    }
    __syncthreads();
    int excl = woffS[wv] + (s - sum);   // exclusive prefix of this thread's chunk
#pragma unroll
    for (int j = 0; j < CHUNK; ++j) {
        int idx = base + j;
        if (idx < N_NODES) {
            int v = excl + local[j];
            off[idx] = v;
            woff[idx] = v;
        }
    }
    if (tid == 0) off[N_NODES] = N_EDGES;
}

__global__ __launch_bounds__(256) void scatter_kernel(const int* __restrict__ srcIdx,
                                                      const int* __restrict__ dstIdx,
                                                      int* __restrict__ woff,
                                                      int* __restrict__ posOf,
                                                      int* __restrict__ srcP) {
    int e = blockIdx.x * 256 + threadIdx.x;
    if (e < N_EDGES) {
        int pos = atomicAdd(&woff[dstIdx[e]], 1);
        posOf[e] = pos;
        srcP[pos] = srcIdx[e];
    }
}

// ---------- Kernel 4: node-centric softmax + aggregation + residual + LayerNorm ----------
// One WAVE per node, 4 channels per lane. Zero LDS, zero barriers; xl gather
// is one 8B vector load per lane (512B coalesced per wave per edge).
// srcP/alphaP indirection software-pipelined depth 2.
__global__ __launch_bounds__(256) void aggregate_ln(const int* __restrict__ off,
                                                    const int* __restrict__ srcP,
                                                    const float* __restrict__ alphaP,
                                                    const unsigned short* __restrict__ xl,
                                                    const float* __restrict__ res,
                                                    const float* __restrict__ biasc,
                                                    const float* __restrict__ gamma,
                                                    const float* __restrict__ beta,
                                                    float* __restrict__ out) {
    int wv = threadIdx.x >> 6, lane = threadIdx.x & 63;
    int i = blockIdx.x * 4 + wv;            // 12500 blocks * 4 waves = 50000 exact
    int beg = off[i], end = off[i + 1];
    int h = lane >> 3;                      // head of channels lane*4..lane*4+3

    float acc0 = 0.f, acc1 = 0.f, acc2 = 0.f, acc3 = 0.f, s = 0.f;

    int p = beg;
    int src_n = 0; float a_n = 0.f;
    if (p < end) {
        src_n = srcP[p];
        a_n   = alphaP[(size_t)p * 8 + h];
    }
    while (p < end) {
        int src = src_n; float a = a_n;
        int pn = p + 1;
        if (pn < end) {                     // prefetch next indirection
            src_n = srcP[pn];
            a_n   = alphaP[(size_t)pn * 8 + h];
        }
        ushort4 v = *(const ushort4*)(xl + (size_t)src * D_MODEL + lane * 4);
        float w = __expf(a);
        s += w;
        acc0 = fmaf(w, bf2f(v.x), acc0);
        acc1 = fmaf(w, bf2f(v.y), acc1);
        acc2 = fmaf(w, bf2f(v.z), acc2);
        acc3 = fmaf(w, bf2f(v.w), acc3);
        p = pn;
    }

    float rs = (end > beg) ? (1.f / s) : 0.f;
    float4 r4 = *(const float4*)(res + (size_t)i * D_MODEL + lane * 4);
    float4 b4 = *(const float4*)(biasc + lane * 4);
    float v0 = acc0 * rs + r4.x + b4.x;
    float v1 = acc1 * rs + r4.y + b4.y;
    float v2 = acc2 * rs + r4.z + b4.z;
    float v3 = acc3 * rs + r4.w + b4.w;

    // LayerNorm over 256 channels = full-wave reduce of per-lane 4-sums
    float sum = v0 + v1 + v2 + v3;
    float sq  = v0 * v0 + v1 * v1 + v2 * v2 + v3 * v3;
#pragma unroll
    for (int msk = 32; msk >= 1; msk >>= 1) {
        sum += __shfl_xor(sum, msk);
        sq  += __shfl_xor(sq, msk);
    }
    float mu  = sum * (1.f / 256.f);
    float var = sq * (1.f / 256.f) - mu * mu;
    var = fmaxf(var, 0.f);
    float inv = rsqrtf(var + LN_EPS);

    float4 g4 = *(const float4*)(gamma + lane * 4);
    float4 be4 = *(const float4*)(beta + lane * 4);
    float4 o4;
    o4.x = (v0 - mu) * inv * g4.x + be4.x;
    o4.y = (v1 - mu) * inv * g4.y + be4.y;
    o4.z = (v2 - mu) * inv * g4.z + be4.z;
    o4.w = (v3 - mu) * inv * g4.w + be4.w;
    *(float4*)(out + (size_t)i * D_MODEL + lane * 4) = o4;
}

extern "C" void kernel_launch(void* const* d_in, const int* in_sizes, int n_in,
                              void* d_out, int out_size, void* d_ws, size_t ws_size,
                              hipStream_t stream) {
    const float* x         = (const float*)d_in[0];
    const float* edge_attr = (const float*)d_in[1];
    const int*   edge_index= (const int*)d_in[2];
    const float* Wl        = (const float*)d_in[3];
    const float* bl        = (const float*)d_in[4];
    const float* Wr        = (const float*)d_in[5];
    const float* br        = (const float*)d_in[6];
    const float* We        = (const float*)d_in[7];
    const float* att       = (const float*)d_in[8];
    const float* Wres      = (const float*)d_in[9];
    const float* biasc     = (const float*)d_in[10];
    const float* gamma     = (const float*)d_in[11];
    const float* beta      = (const float*)d_in[12];
    const int* srcIdx = edge_index;
    const int* dstIdx = edge_index + N_EDGES;
    float* out = (float*)d_out;

    // workspace layout
    char* ws = (char*)d_ws;
    unsigned short* xl  = (unsigned short*)ws;                       // N*256 bf16
    unsigned short* xr  = xl + (size_t)N_NODES * D_MODEL;            // N*256 bf16
    unsigned short* xbf = xr + (size_t)N_NODES * D_MODEL;            // N*256 bf16
    unsigned short* Wbf = xbf + (size_t)N_NODES * D_MODEL;           // 3*256*256 bf16
    float* res    = (float*)(Wbf + 3 * 65536);                       // N*256 f32
    float* alphaP = res + (size_t)N_NODES * D_MODEL;                 // E*8 f32 (CSR order)
    int* cnt   = (int*)(alphaP + (size_t)N_EDGES * 8);               // N
    int* off   = cnt + N_NODES;                                      // N+1
    int* woff  = off + (N_NODES + 1);                                // N
    int* posOf = woff + N_NODES;                                     // E
    int* srcP  = posOf + N_EDGES;                                    // E
    (void)ws_size; (void)n_in; (void)in_sizes; (void)out_size;

    hipMemsetAsync(cnt, 0, N_NODES * sizeof(int), stream);

    cvt_bf16_kernel<<<(N_NODES * D_MODEL / 8 + 255) / 256, 256, 0, stream>>>(x, xbf, N_NODES * D_MODEL / 8);
    cvt_bf16_kernel<<<32, 256, 0, stream>>>(Wl,   Wbf,             65536 / 8);
    cvt_bf16_kernel<<<32, 256, 0, stream>>>(Wr,   Wbf + 65536,     65536 / 8);
    cvt_bf16_kernel<<<32, 256, 0, stream>>>(Wres, Wbf + 2 * 65536, 65536 / 8);

    dim3 g1((N_NODES + 63) / 64, 3);
    node_gemm<<<g1, 256, 0, stream>>>(xbf, Wbf, bl, br, xl, xr, res);

    hist_kernel<<<(N_EDGES + 255) / 256, 256, 0, stream>>>(dstIdx, cnt);
    scan_kernel<<<1, 1024, 0, stream>>>(cnt, off, woff);
    scatter_kernel<<<(N_EDGES + 255) / 256, 256, 0, stream>>>(srcIdx, dstIdx, woff, posOf, srcP);

    edge_logits<<<1280, 256, 0, stream>>>(edge_attr, We, att, srcIdx, dstIdx, posOf, xl, xr, alphaP);

    aggregate_ln<<<N_NODES / 4, 256, 0, stream>>>(off, srcP, alphaP, xl, res,
                                                  biasc, gamma, beta, out);
}